// Round 5
// baseline (378.743 us; speedup 1.0000x reference)
//
#include <hip/hip_runtime.h>
#include <math.h>

#define EPS 1e-5f

__device__ __forceinline__ float gelu_exact(float x) {
    return 0.5f * x * (1.0f + erff(x * 0.7071067811865476f));
}

// ---- block reductions for finalize (192 threads = 3 waves) ----
__device__ float block_sum(float v, float* red) {
    int lane = threadIdx.x & 63, wid = threadIdx.x >> 6;
#pragma unroll
    for (int off = 32; off > 0; off >>= 1) v += __shfl_down(v, off, 64);
    if (lane == 0) red[wid] = v;
    __syncthreads();
    int nw = ((int)blockDim.x + 63) >> 6;
    float s = red[0];
    for (int w = 1; w < nw; w++) s += red[w];
    __syncthreads();
    return s;
}

__device__ float block_max(float v, float* red) {
    int lane = threadIdx.x & 63, wid = threadIdx.x >> 6;
#pragma unroll
    for (int off = 32; off > 0; off >>= 1) v = fmaxf(v, __shfl_down(v, off, 64));
    if (lane == 0) red[wid] = v;
    __syncthreads();
    int nw = ((int)blockDim.x + 63) >> 6;
    float s = red[0];
    for (int w = 1; w < nw; w++) s = fmaxf(s, red[w]);
    __syncthreads();
    return s;
}

// ---- threefry2x32-20 (JAX PRNG), partitionable scheme (verified round 1) ----
__device__ void threefry2x32(unsigned k0, unsigned k1, unsigned x0, unsigned x1,
                             unsigned& o0, unsigned& o1) {
    unsigned ks[3] = {k0, k1, k0 ^ k1 ^ 0x1BD11BDAu};
    const unsigned rot[2][4] = {{13u, 15u, 26u, 6u}, {17u, 29u, 16u, 24u}};
    x0 += ks[0]; x1 += ks[1];
#pragma unroll
    for (int i = 0; i < 5; i++) {
#pragma unroll
        for (int j = 0; j < 4; j++) {
            unsigned r = rot[i & 1][j];
            x0 += x1;
            x1 = (x1 << r) | (x1 >> (32 - r));
            x1 ^= x0;
        }
        x0 += ks[(i + 1) % 3];
        x1 += ks[(i + 2) % 3] + (unsigned)(i + 1);
    }
    o0 = x0; o1 = x1;
}

__device__ float gumbel_at(int j) {
    unsigned o0, o1;
    threefry2x32(0u, 42u, 0u, (unsigned)j, o0, o1);
    unsigned bits = o0 ^ o1;
    float f = __uint_as_float((bits >> 9) | 0x3F800000u) - 1.0f;  // [0,1)
    float u = fmaxf(f + 1.17549435e-38f, 1.17549435e-38f);
    return -logf(-logf(u));
}

// ---- paired 2-value reduction over 128 threads (2 waves) ----
__device__ void bsum2_128(float& a, float& b, float (*red)[2]) {
    int lane = threadIdx.x & 63, wid = threadIdx.x >> 6;
#pragma unroll
    for (int off = 32; off > 0; off >>= 1) {
        a += __shfl_xor(a, off, 64);
        b += __shfl_xor(b, off, 64);
    }
    if (lane == 0) { red[wid][0] = a; red[wid][1] = b; }
    __syncthreads();
    a = red[0][0] + red[1][0];
    b = red[0][1] + red[1][1];
}

// ---- encode both inputs in one launch: grid (512+128, 32), block 128. ----
__global__ void encode_kernel(const float* __restrict__ x_lt, const float* __restrict__ x_st,
                              const float* __restrict__ Ws, const float* __restrict__ bs,
                              const float* __restrict__ Wt, const float* __restrict__ bt,
                              float* __restrict__ e_lt, float* __restrict__ e_st) {
    const int H = 128;
    int b = blockIdx.y, t = threadIdx.x;
    const float* x;
    float* e;
    int L, l;
    if (blockIdx.x < 512) { x = x_lt; e = e_lt; L = 512; l = blockIdx.x; }
    else { x = x_st; e = e_st; L = 128; l = blockIdx.x - 512; }
    __shared__ float part[117];
    __shared__ float seas[9], mmv[9];
    __shared__ float redA[2][2], redB[2][2];
    const float* xb = x + (size_t)b * L * 9;
    if (t < 117) {
        int c = t / 13, g = t % 13;
        int lj0 = l + 2 * g - 12;
        lj0 = lj0 < 0 ? 0 : (lj0 >= L ? L - 1 : lj0);
        float s = xb[(size_t)lj0 * 9 + c];
        if (g < 12) {
            int lj1 = l + 2 * g - 11;
            lj1 = lj1 < 0 ? 0 : (lj1 >= L ? L - 1 : lj1);
            s += xb[(size_t)lj1 * 9 + c];
        }
        part[t] = s;
    }
    __syncthreads();
    if (t < 9) {
        float s = 0.f;
        for (int g = 0; g < 13; g++) s += part[t * 13 + g];
        float x0 = xb[t];
        float mm = (s - 25.f * x0) * (1.0f / 25.0f);
        float xd = xb[(size_t)l * 9 + t] - x0;
        mmv[t] = mm;
        seas[t] = xd - mm;
    }
    __syncthreads();
    float ys = bs[t], yt = bt[t];
#pragma unroll
    for (int c = 0; c < 9; c++) {
        ys += seas[c] * Ws[c * H + t];
        yt += mmv[c] * Wt[c * H + t];
    }
    float sa = ys, sb = yt;
    bsum2_128(sa, sb, redA);
    float ms = sa * (1.0f / 128.0f), mt = sb * (1.0f / 128.0f);
    float ds = ys - ms, dt = yt - mt;
    float qa = ds * ds, qb = dt * dt;
    bsum2_128(qa, qb, redB);
    float gy = gelu_exact(ds * rsqrtf(qa * (1.0f / 128.0f) + EPS));
    float gt = gelu_exact(dt * rsqrtf(qb * (1.0f / 128.0f) + EPS));
    e[((size_t)b * L + l) * H + t] = gy + gt;
}

// ---- wave-autonomous Linear -> InstanceNorm -> GELU, transposed-output. ----
template <int K, int N, int WR, bool TRANS>
__global__ __launch_bounds__(256) void lbr_wave(
    const float* __restrict__ A, int S, int ABOFF,
    const float* __restrict__ W, const float* __restrict__ bias,
    float* __restrict__ out, int OROWS, int OBOFF) {
    constexpr int CG = N / 4;        // lanes covering the N dimension
    constexpr int SG = 64 / CG;      // row-subgroups per wave
    constexpr int RW = SG * WR;      // rows per wave
    constexpr int MT = 4 * RW;       // rows per block
    constexpr int LOG2MT = (MT == 8) ? 3 : ((MT == 16) ? 4 : 5);
    constexpr int STAGE = 4 * RW * K;
    constexpr int TILE = TRANS ? MT * (N + 4) : 0;
    constexpr int LSZ = STAGE > TILE ? STAGE : TILE;
    __shared__ float lds[LSZ];
    const int t = threadIdx.x;
    const int w = t >> 6, ln = t & 63;
    const int sg = ln / CG;
    const int n0 = (ln % CG) * 4;
    const int b = blockIdx.y;
    const int r0b = blockIdx.x * MT;
    const int r0w = r0b + w * RW;
    float* As = lds + w * RW * K;
    const float* Ab = A + (size_t)b * ABOFF;
    for (int idx = ln; idx < RW * (K / 4); idx += 64) {
        int rr = idx / (K / 4), kk = idx % (K / 4);
        float4 v = *(const float4*)(Ab + (size_t)(r0w + rr) * S + kk * 4);
        *(float4*)(As + rr * K + kk * 4) = v;
    }
    float4 acc[WR];
    {
        float4 bv = *(const float4*)(bias + n0);
#pragma unroll
        for (int j = 0; j < WR; j++) acc[j] = bv;
    }
    const float* ap = As + (sg * WR) * K;
    const float* wp = W + n0;
#pragma unroll 8
    for (int k = 0; k < K; k++) {
        float4 wv = *(const float4*)wp;
        wp += N;
#pragma unroll
        for (int j = 0; j < WR; j++) {
            float a = ap[j * K + k];
            acc[j].x += a * wv.x;
            acc[j].y += a * wv.y;
            acc[j].z += a * wv.z;
            acc[j].w += a * wv.w;
        }
    }
    float4 res[WR];
#pragma unroll
    for (int j = 0; j < WR; j++) {
        float s = acc[j].x + acc[j].y + acc[j].z + acc[j].w;
#pragma unroll
        for (int off = CG / 2; off > 0; off >>= 1) s += __shfl_xor(s, off, 64);
        float m = s * (1.0f / (float)N);
        float dx = acc[j].x - m, dy = acc[j].y - m, dz = acc[j].z - m, dw = acc[j].w - m;
        float q = dx * dx + dy * dy + dz * dz + dw * dw;
#pragma unroll
        for (int off = CG / 2; off > 0; off >>= 1) q += __shfl_xor(q, off, 64);
        float inv = rsqrtf(q * (1.0f / (float)N) + EPS);
        res[j].x = gelu_exact(dx * inv);
        res[j].y = gelu_exact(dy * inv);
        res[j].z = gelu_exact(dz * inv);
        res[j].w = gelu_exact(dw * inv);
    }
    if constexpr (TRANS) {
        __syncthreads();
#pragma unroll
        for (int j = 0; j < WR; j++) {
            int rl = w * RW + sg * WR + j;
            *(float4*)(lds + rl * (N + 4) + n0) = res[j];
        }
        __syncthreads();
        float* ob = out + (size_t)b * OBOFF + r0b;
        for (int e = t; e < MT * N; e += 256) {
            int r = e & (MT - 1), n = e >> LOG2MT;
            ob[(size_t)n * OROWS + r] = lds[r * (N + 4) + n];
        }
    } else {
        float* ob = out + (size_t)b * OBOFF;
#pragma unroll
        for (int j = 0; j < WR; j++) {
            int row = r0w + sg * WR + j;
            *(float4*)(ob + (size_t)row * N + n0) = res[j];
        }
    }
}

// ---- fused logits + gumbel-softmax(hard) selection. grid 32 (b), block 256. ----
__global__ void logits_select(const float* __restrict__ O6, const float* __restrict__ Wr,
                              const float* __restrict__ br,
                              float* __restrict__ sel_w, int* __restrict__ sel_r) {
    int b = blockIdx.x, t = threadIdx.x;
    const float* ob = O6 + (size_t)b * 8192;
    float acc[8] = {0, 0, 0, 0, 0, 0, 0, 0};
#pragma unroll 4
    for (int q = 0; q < 32; q++) {
        int i = q * 256 + t;
        int l4 = i >> 7, h = i & 127;
        float v = ob[h * 64 + l4];
        const float* wr = Wr + (size_t)i * 8;
#pragma unroll
        for (int j = 0; j < 8; j++) acc[j] += v * wr[j];
    }
#pragma unroll
    for (int j = 0; j < 8; j++)
#pragma unroll
        for (int off = 32; off > 0; off >>= 1) acc[j] += __shfl_xor(acc[j], off, 64);
    __shared__ float red[4][8];
    int lane = t & 63, wid = t >> 6;
    if (lane == 0)
        for (int j = 0; j < 8; j++) red[wid][j] = acc[j];
    __syncthreads();
    if (t == 0) {
        float z[8];
        for (int j = 0; j < 8; j++) {
            float lg = br[j] + red[0][j] + red[1][j] + red[2][j] + red[3][j];
            z[j] = lg + gumbel_at(b * 8 + j);
        }
        int am = 0;
        float zm = z[0];
        for (int j = 1; j < 8; j++)
            if (z[j] > zm) { zm = z[j]; am = j; }
        float ssum = 0.f;
        for (int j = 0; j < 8; j++) ssum += expf(z[j] - zm);
        float s = 1.0f / ssum;
        sel_w[b] = (1.0f - s) + s;
        sel_r[b] = am;
    }
}

// ---- regime-grouped, K-split einsum; scans sel_r directly. grid (128 n, 8 r). ----
__global__ void einsum_nsplit(const float* __restrict__ e_st, const float* __restrict__ proto,
                              const int* __restrict__ sel_r, float* __restrict__ part) {
    int n = blockIdx.x, r = blockIdx.y, t = threadIdx.x;  // t = m*3+o
    __shared__ int loc[32];
    __shared__ int s_gs;
    if (t == 0) {
        int g = 0;
        for (int bb = 0; bb < 32; bb++)
            if (sel_r[bb] == r) loc[g++] = bb;
        s_gs = g;
    }
    __syncthreads();
    int gs = s_gs;
    if (gs == 0) return;
    __shared__ float es[8][128];
    const float* pb = proto + ((size_t)r * 128 + n) * 128 * 192;
    for (int s0 = 0; s0 < gs; s0 += 8) {
        int np = gs - s0 < 8 ? gs - s0 : 8;
        __syncthreads();
        for (int i = t; i < 1024; i += 192) {
            int sb = i >> 7, h = i & 127;
            if (sb < np) {
                int b = loc[s0 + sb];
                es[sb][h] = e_st[((size_t)b * 128 + n) * 128 + h];
            } else {
                es[sb][h] = 0.f;
            }
        }
        __syncthreads();
        float a0 = 0.f, a1 = 0.f, a2 = 0.f, a3 = 0.f;
        float a4 = 0.f, a5 = 0.f, a6 = 0.f, a7 = 0.f;
#pragma unroll 8
        for (int h = 0; h < 128; h++) {
            float p = pb[h * 192 + t];
            a0 += es[0][h] * p; a1 += es[1][h] * p;
            a2 += es[2][h] * p; a3 += es[3][h] * p;
            a4 += es[4][h] * p; a5 += es[5][h] * p;
            a6 += es[6][h] * p; a7 += es[7][h] * p;
        }
        float av[8] = {a0, a1, a2, a3, a4, a5, a6, a7};
#pragma unroll
        for (int sb = 0; sb < 8; sb++) {
            if (sb < np) {
                int b = loc[s0 + sb];
                part[((size_t)b * 128 + n) * 192 + t] = av[sb];
            }
        }
    }
}

// ---- reduce 128 n-partials, scale by regime weight, softmax over 192 ----
__global__ void finalize_kernel(const float* __restrict__ part, const float* __restrict__ sel_w,
                                float* __restrict__ out) {
    int b = blockIdx.x, t = threadIdx.x;
    __shared__ float red[4];
    float v = 0.f;
#pragma unroll 8
    for (int c = 0; c < 128; c++) v += part[((size_t)b * 128 + c) * 192 + t];
    v *= sel_w[b];
    float mx = block_max(v, red);
    float e = expf(v - mx);
    float s = block_sum(e, red);
    out[(size_t)b * 192 + t] = e / s;
}

extern "C" void kernel_launch(void* const* d_in, const int* in_sizes, int n_in,
                              void* d_out, int out_size, void* d_ws, size_t ws_size,
                              hipStream_t stream) {
    const float* in_lt = (const float*)d_in[0];
    const float* in_st = (const float*)d_in[1];
    const float* Ws  = (const float*)d_in[2];  const float* bs  = (const float*)d_in[3];
    const float* Wt  = (const float*)d_in[4];  const float* bt  = (const float*)d_in[5];
    const float* Wh1 = (const float*)d_in[6];  const float* bh1 = (const float*)d_in[7];
    const float* Wl1 = (const float*)d_in[8];  const float* bl1 = (const float*)d_in[9];
    const float* Wh2 = (const float*)d_in[10]; const float* bh2 = (const float*)d_in[11];
    const float* Wl2 = (const float*)d_in[12]; const float* bl2 = (const float*)d_in[13];
    const float* Wh3 = (const float*)d_in[14]; const float* bh3 = (const float*)d_in[15];
    const float* Wl3 = (const float*)d_in[16]; const float* bl3 = (const float*)d_in[17];
    const float* Wr  = (const float*)d_in[18]; const float* br  = (const float*)d_in[19];
    const float* proto = (const float*)d_in[20];
    float* out = (float*)d_out;

    float* ws = (float*)d_ws;
    size_t off = 0;
    float* e_lt = ws + off; off += (size_t)32 * 512 * 128;   // [(b,l)][h]
    float* e_st = ws + off; off += (size_t)32 * 128 * 128;   // [b,n][h]
    float* O1T = ws + off; off += (size_t)128 * 16384;       // [h][(b,l)]
    float* O2T = ws + off; off += (size_t)256 * 4096;        // [l2][(b,h)]
    float* O3T = ws + off; off += (size_t)128 * 8192;        // [h][(b,l2)]
    float* O4T = ws + off; off += (size_t)128 * 4096;        // [l3][(b,h)]
    float* O5T = ws + off; off += (size_t)128 * 4096;        // [h][(b,l3)]
    float* O6 = ws + off; off += (size_t)32 * 128 * 64;      // [b][h][l4]
    float* part = ws + off; off += (size_t)32 * 128 * 192;
    float* sel_w = ws + off; off += 32;
    int* sel_r = (int*)(ws + off); off += 32;

    encode_kernel<<<dim3(640, 32), 128, 0, stream>>>(in_lt, in_st, Ws, bs, Wt, bt, e_lt, e_st);
    // h1: flat 16384 rows, K=128, N=128 -> O1T[h][16384]
    lbr_wave<128, 128, 2, true><<<dim3(1024, 1), 256, 0, stream>>>(
        e_lt, 128, 0, Wh1, bh1, O1T, 16384, 0);
    // l1: rows=h(128)/b, K=512, N=256; WR=4 (MT=16) -> O2T[l2][4096]
    lbr_wave<512, 256, 4, true><<<dim3(8, 32), 256, 0, stream>>>(
        O1T, 16384, 512, Wl1, bl1, O2T, 4096, 128);
    // h2: rows=l2(256)/b, K=128, N=128; WR=4 (MT=32) -> O3T[h][8192]
    lbr_wave<128, 128, 4, true><<<dim3(8, 32), 256, 0, stream>>>(
        O2T, 4096, 128, Wh2, bh2, O3T, 8192, 256);
    // l2: rows=h(128)/b, K=256, N=128; WR=2 (MT=16) -> O4T[l3][4096]
    lbr_wave<256, 128, 2, true><<<dim3(8, 32), 256, 0, stream>>>(
        O3T, 8192, 256, Wl2, bl2, O4T, 4096, 128);
    // h3: rows=l3(128)/b, K=128, N=128; WR=2 (MT=16) -> O5T[h][4096]
    lbr_wave<128, 128, 2, true><<<dim3(8, 32), 256, 0, stream>>>(
        O4T, 4096, 128, Wh3, bh3, O5T, 4096, 128);
    // l3: rows=h(128)/b, K=128, N=64; natural out [b][h][l4]
    lbr_wave<128, 64, 1, false><<<dim3(8, 32), 256, 0, stream>>>(
        O5T, 4096, 128, Wl3, bl3, O6, 0, 8192);
    logits_select<<<32, 256, 0, stream>>>(O6, Wr, br, sel_w, sel_r);
    einsum_nsplit<<<dim3(128, 8), 192, 0, stream>>>(e_st, proto, sel_r, part);
    finalize_kernel<<<32, 192, 0, stream>>>(part, sel_w, out);
}

// Round 6
// 362.227 us; speedup vs baseline: 1.0456x; 1.0456x over previous
//
#include <hip/hip_runtime.h>
#include <math.h>

#define EPS 1e-5f

__device__ __forceinline__ float gelu_exact(float x) {
    return 0.5f * x * (1.0f + erff(x * 0.7071067811865476f));
}

// ---- block reductions for finalize (192 threads = 3 waves) ----
__device__ float block_sum(float v, float* red) {
    int lane = threadIdx.x & 63, wid = threadIdx.x >> 6;
#pragma unroll
    for (int off = 32; off > 0; off >>= 1) v += __shfl_down(v, off, 64);
    if (lane == 0) red[wid] = v;
    __syncthreads();
    int nw = ((int)blockDim.x + 63) >> 6;
    float s = red[0];
    for (int w = 1; w < nw; w++) s += red[w];
    __syncthreads();
    return s;
}

__device__ float block_max(float v, float* red) {
    int lane = threadIdx.x & 63, wid = threadIdx.x >> 6;
#pragma unroll
    for (int off = 32; off > 0; off >>= 1) v = fmaxf(v, __shfl_down(v, off, 64));
    if (lane == 0) red[wid] = v;
    __syncthreads();
    int nw = ((int)blockDim.x + 63) >> 6;
    float s = red[0];
    for (int w = 1; w < nw; w++) s = fmaxf(s, red[w]);
    __syncthreads();
    return s;
}

// ---- threefry2x32-20 (JAX PRNG), partitionable scheme (verified round 1) ----
__device__ void threefry2x32(unsigned k0, unsigned k1, unsigned x0, unsigned x1,
                             unsigned& o0, unsigned& o1) {
    unsigned ks[3] = {k0, k1, k0 ^ k1 ^ 0x1BD11BDAu};
    const unsigned rot[2][4] = {{13u, 15u, 26u, 6u}, {17u, 29u, 16u, 24u}};
    x0 += ks[0]; x1 += ks[1];
#pragma unroll
    for (int i = 0; i < 5; i++) {
#pragma unroll
        for (int j = 0; j < 4; j++) {
            unsigned r = rot[i & 1][j];
            x0 += x1;
            x1 = (x1 << r) | (x1 >> (32 - r));
            x1 ^= x0;
        }
        x0 += ks[(i + 1) % 3];
        x1 += ks[(i + 2) % 3] + (unsigned)(i + 1);
    }
    o0 = x0; o1 = x1;
}

__device__ float gumbel_at(int j) {
    unsigned o0, o1;
    threefry2x32(0u, 42u, 0u, (unsigned)j, o0, o1);
    unsigned bits = o0 ^ o1;
    float f = __uint_as_float((bits >> 9) | 0x3F800000u) - 1.0f;  // [0,1)
    float u = fmaxf(f + 1.17549435e-38f, 1.17549435e-38f);
    return -logf(-logf(u));
}

// ---- paired 2-value reduction over 128 threads (2 waves) ----
__device__ void bsum2_128(float& a, float& b, float (*red)[2]) {
    int lane = threadIdx.x & 63, wid = threadIdx.x >> 6;
#pragma unroll
    for (int off = 32; off > 0; off >>= 1) {
        a += __shfl_xor(a, off, 64);
        b += __shfl_xor(b, off, 64);
    }
    if (lane == 0) { red[wid][0] = a; red[wid][1] = b; }
    __syncthreads();
    a = red[0][0] + red[1][0];
    b = red[0][1] + red[1][1];
}

// ---- encode both inputs in one launch: grid (512+128, 32), block 128. ----
__global__ void encode_kernel(const float* __restrict__ x_lt, const float* __restrict__ x_st,
                              const float* __restrict__ Ws, const float* __restrict__ bs,
                              const float* __restrict__ Wt, const float* __restrict__ bt,
                              float* __restrict__ e_lt, float* __restrict__ e_st) {
    const int H = 128;
    int b = blockIdx.y, t = threadIdx.x;
    const float* x;
    float* e;
    int L, l;
    if (blockIdx.x < 512) { x = x_lt; e = e_lt; L = 512; l = blockIdx.x; }
    else { x = x_st; e = e_st; L = 128; l = blockIdx.x - 512; }
    __shared__ float part[117];
    __shared__ float seas[9], mmv[9];
    __shared__ float redA[2][2], redB[2][2];
    const float* xb = x + (size_t)b * L * 9;
    if (t < 117) {
        int c = t / 13, g = t % 13;
        int lj0 = l + 2 * g - 12;
        lj0 = lj0 < 0 ? 0 : (lj0 >= L ? L - 1 : lj0);
        float s = xb[(size_t)lj0 * 9 + c];
        if (g < 12) {
            int lj1 = l + 2 * g - 11;
            lj1 = lj1 < 0 ? 0 : (lj1 >= L ? L - 1 : lj1);
            s += xb[(size_t)lj1 * 9 + c];
        }
        part[t] = s;
    }
    __syncthreads();
    if (t < 9) {
        float s = 0.f;
        for (int g = 0; g < 13; g++) s += part[t * 13 + g];
        float x0 = xb[t];
        float mm = (s - 25.f * x0) * (1.0f / 25.0f);
        float xd = xb[(size_t)l * 9 + t] - x0;
        mmv[t] = mm;
        seas[t] = xd - mm;
    }
    __syncthreads();
    float ys = bs[t], yt = bt[t];
#pragma unroll
    for (int c = 0; c < 9; c++) {
        ys += seas[c] * Ws[c * H + t];
        yt += mmv[c] * Wt[c * H + t];
    }
    float sa = ys, sb = yt;
    bsum2_128(sa, sb, redA);
    float ms = sa * (1.0f / 128.0f), mt = sb * (1.0f / 128.0f);
    float ds = ys - ms, dt = yt - mt;
    float qa = ds * ds, qb = dt * dt;
    bsum2_128(qa, qb, redB);
    float gy = gelu_exact(ds * rsqrtf(qa * (1.0f / 128.0f) + EPS));
    float gt = gelu_exact(dt * rsqrtf(qb * (1.0f / 128.0f) + EPS));
    e[((size_t)b * L + l) * H + t] = gy + gt;
}

// ---- wave-autonomous Linear -> InstanceNorm -> GELU, transposed-output.
// K-loop steps by 4: one float4 A-read per row from wave-private LDS +
// 4 float4 W loads, 16*WR FMAs per step. ----
template <int K, int N, int WR, bool TRANS>
__global__ __launch_bounds__(256) void lbr_wave(
    const float* __restrict__ A, int S, int ABOFF,
    const float* __restrict__ W, const float* __restrict__ bias,
    float* __restrict__ out, int OROWS, int OBOFF) {
    constexpr int CG = N / 4;        // lanes covering the N dimension
    constexpr int SG = 64 / CG;      // row-subgroups per wave
    constexpr int RW = SG * WR;      // rows per wave
    constexpr int MT = 4 * RW;       // rows per block
    constexpr int LOG2MT = (MT == 8) ? 3 : ((MT == 16) ? 4 : 5);
    constexpr int STAGE = 4 * RW * K;
    constexpr int TILE = TRANS ? MT * (N + 4) : 0;
    constexpr int LSZ = STAGE > TILE ? STAGE : TILE;
    __shared__ float lds[LSZ];
    const int t = threadIdx.x;
    const int w = t >> 6, ln = t & 63;
    const int sg = ln / CG;
    const int n0 = (ln % CG) * 4;
    const int b = blockIdx.y;
    const int r0b = blockIdx.x * MT;
    const int r0w = r0b + w * RW;
    float* As = lds + w * RW * K;
    const float* Ab = A + (size_t)b * ABOFF;
    for (int idx = ln; idx < RW * (K / 4); idx += 64) {
        int rr = idx / (K / 4), kk = idx % (K / 4);
        float4 v = *(const float4*)(Ab + (size_t)(r0w + rr) * S + kk * 4);
        *(float4*)(As + rr * K + kk * 4) = v;
    }
    float4 acc[WR];
    {
        float4 bv = *(const float4*)(bias + n0);
#pragma unroll
        for (int j = 0; j < WR; j++) acc[j] = bv;
    }
    const float* ap = As + (sg * WR) * K;
    const float* wp = W + n0;
#pragma unroll 2
    for (int k = 0; k < K; k += 4) {
        float4 w0 = *(const float4*)(wp);
        float4 w1 = *(const float4*)(wp + N);
        float4 w2 = *(const float4*)(wp + 2 * N);
        float4 w3 = *(const float4*)(wp + 3 * N);
        wp += 4 * N;
#pragma unroll
        for (int j = 0; j < WR; j++) {
            float4 a4 = *(const float4*)(ap + j * K + k);
            acc[j].x += a4.x * w0.x; acc[j].y += a4.x * w0.y;
            acc[j].z += a4.x * w0.z; acc[j].w += a4.x * w0.w;
            acc[j].x += a4.y * w1.x; acc[j].y += a4.y * w1.y;
            acc[j].z += a4.y * w1.z; acc[j].w += a4.y * w1.w;
            acc[j].x += a4.z * w2.x; acc[j].y += a4.z * w2.y;
            acc[j].z += a4.z * w2.z; acc[j].w += a4.z * w2.w;
            acc[j].x += a4.w * w3.x; acc[j].y += a4.w * w3.y;
            acc[j].z += a4.w * w3.z; acc[j].w += a4.w * w3.w;
        }
    }
    float4 res[WR];
#pragma unroll
    for (int j = 0; j < WR; j++) {
        float s = acc[j].x + acc[j].y + acc[j].z + acc[j].w;
#pragma unroll
        for (int off = CG / 2; off > 0; off >>= 1) s += __shfl_xor(s, off, 64);
        float m = s * (1.0f / (float)N);
        float dx = acc[j].x - m, dy = acc[j].y - m, dz = acc[j].z - m, dw = acc[j].w - m;
        float q = dx * dx + dy * dy + dz * dz + dw * dw;
#pragma unroll
        for (int off = CG / 2; off > 0; off >>= 1) q += __shfl_xor(q, off, 64);
        float inv = rsqrtf(q * (1.0f / (float)N) + EPS);
        res[j].x = gelu_exact(dx * inv);
        res[j].y = gelu_exact(dy * inv);
        res[j].z = gelu_exact(dz * inv);
        res[j].w = gelu_exact(dw * inv);
    }
    if constexpr (TRANS) {
        __syncthreads();
#pragma unroll
        for (int j = 0; j < WR; j++) {
            int rl = w * RW + sg * WR + j;
            *(float4*)(lds + rl * (N + 4) + n0) = res[j];
        }
        __syncthreads();
        float* ob = out + (size_t)b * OBOFF + r0b;
        for (int e = t; e < MT * N; e += 256) {
            int r = e & (MT - 1), n = e >> LOG2MT;
            ob[(size_t)n * OROWS + r] = lds[r * (N + 4) + n];
        }
    } else {
        float* ob = out + (size_t)b * OBOFF;
#pragma unroll
        for (int j = 0; j < WR; j++) {
            int row = r0w + sg * WR + j;
            *(float4*)(ob + (size_t)row * N + n0) = res[j];
        }
    }
}

// ---- fused logits + gumbel-softmax(hard) selection. grid 32 (b), block 256.
// O6[b] staged in LDS with +68 row pitch (conflict-free strided readout);
// Wr read as 2x float4 per row (coalesced 32B/lane). ----
__global__ __launch_bounds__(256) void logits_select(
    const float* __restrict__ O6, const float* __restrict__ Wr,
    const float* __restrict__ br, float* __restrict__ sel_w, int* __restrict__ sel_r) {
    int b = blockIdx.x, t = threadIdx.x;
    __shared__ float sO6[128 * 68];
    __shared__ float red[4][8];
    const float4* ob4 = (const float4*)(O6 + (size_t)b * 8192);
    for (int i4 = t; i4 < 2048; i4 += 256) {
        float4 v = ob4[i4];
        int p = i4 * 4;
        int h = p >> 6, l4 = p & 63;
        *(float4*)(&sO6[h * 68 + l4]) = v;
    }
    __syncthreads();
    float acc[8] = {0, 0, 0, 0, 0, 0, 0, 0};
#pragma unroll 4
    for (int q = 0; q < 32; q++) {
        int i = q * 256 + t;  // logits flat index: l4 = i>>7, h = i&127
        int l4 = i >> 7, h = i & 127;
        float v = sO6[h * 68 + l4];
        const float4* wr = (const float4*)(Wr + (size_t)i * 8);
        float4 w0 = wr[0], w1 = wr[1];
        acc[0] += v * w0.x; acc[1] += v * w0.y; acc[2] += v * w0.z; acc[3] += v * w0.w;
        acc[4] += v * w1.x; acc[5] += v * w1.y; acc[6] += v * w1.z; acc[7] += v * w1.w;
    }
#pragma unroll
    for (int j = 0; j < 8; j++)
#pragma unroll
        for (int off = 32; off > 0; off >>= 1) acc[j] += __shfl_xor(acc[j], off, 64);
    int lane = t & 63, wid = t >> 6;
    if (lane == 0)
        for (int j = 0; j < 8; j++) red[wid][j] = acc[j];
    __syncthreads();
    if (t == 0) {
        float z[8];
        for (int j = 0; j < 8; j++) {
            float lg = br[j] + red[0][j] + red[1][j] + red[2][j] + red[3][j];
            z[j] = lg + gumbel_at(b * 8 + j);
        }
        int am = 0;
        float zm = z[0];
        for (int j = 1; j < 8; j++)
            if (z[j] > zm) { zm = z[j]; am = j; }
        float ssum = 0.f;
        for (int j = 0; j < 8; j++) ssum += expf(z[j] - zm);
        float s = 1.0f / ssum;
        sel_w[b] = (1.0f - s) + s;
        sel_r[b] = am;
    }
}

// ---- regime-grouped, K-split einsum; scans sel_r directly. grid (128 n, 8 r). ----
__global__ void einsum_nsplit(const float* __restrict__ e_st, const float* __restrict__ proto,
                              const int* __restrict__ sel_r, float* __restrict__ part) {
    int n = blockIdx.x, r = blockIdx.y, t = threadIdx.x;  // t = m*3+o
    __shared__ int loc[32];
    __shared__ int s_gs;
    if (t == 0) {
        int g = 0;
        for (int bb = 0; bb < 32; bb++)
            if (sel_r[bb] == r) loc[g++] = bb;
        s_gs = g;
    }
    __syncthreads();
    int gs = s_gs;
    if (gs == 0) return;
    __shared__ float es[8][128];
    const float* pb = proto + ((size_t)r * 128 + n) * 128 * 192;
    for (int s0 = 0; s0 < gs; s0 += 8) {
        int np = gs - s0 < 8 ? gs - s0 : 8;
        __syncthreads();
        for (int i4 = t; i4 < 256; i4 += 192) {
            int sb = i4 >> 5, h4 = i4 & 31;
            float4 v = make_float4(0.f, 0.f, 0.f, 0.f);
            if (sb < np) {
                int b = loc[s0 + sb];
                v = ((const float4*)(e_st + ((size_t)b * 128 + n) * 128))[h4];
            }
            *(float4*)(&es[sb][h4 * 4]) = v;
        }
        __syncthreads();
        float a0 = 0.f, a1 = 0.f, a2 = 0.f, a3 = 0.f;
        float a4 = 0.f, a5 = 0.f, a6 = 0.f, a7 = 0.f;
#pragma unroll 8
        for (int h = 0; h < 128; h++) {
            float p = pb[h * 192 + t];
            a0 += es[0][h] * p; a1 += es[1][h] * p;
            a2 += es[2][h] * p; a3 += es[3][h] * p;
            a4 += es[4][h] * p; a5 += es[5][h] * p;
            a6 += es[6][h] * p; a7 += es[7][h] * p;
        }
        float av[8] = {a0, a1, a2, a3, a4, a5, a6, a7};
#pragma unroll
        for (int sb = 0; sb < 8; sb++) {
            if (sb < np) {
                int b = loc[s0 + sb];
                part[((size_t)b * 128 + n) * 192 + t] = av[sb];
            }
        }
    }
}

// ---- reduce 128 n-partials, scale by regime weight, softmax over 192 ----
__global__ void finalize_kernel(const float* __restrict__ part, const float* __restrict__ sel_w,
                                float* __restrict__ out) {
    int b = blockIdx.x, t = threadIdx.x;
    __shared__ float red[4];
    float v = 0.f;
#pragma unroll 8
    for (int c = 0; c < 128; c++) v += part[((size_t)b * 128 + c) * 192 + t];
    v *= sel_w[b];
    float mx = block_max(v, red);
    float e = expf(v - mx);
    float s = block_sum(e, red);
    out[(size_t)b * 192 + t] = e / s;
}

extern "C" void kernel_launch(void* const* d_in, const int* in_sizes, int n_in,
                              void* d_out, int out_size, void* d_ws, size_t ws_size,
                              hipStream_t stream) {
    const float* in_lt = (const float*)d_in[0];
    const float* in_st = (const float*)d_in[1];
    const float* Ws  = (const float*)d_in[2];  const float* bs  = (const float*)d_in[3];
    const float* Wt  = (const float*)d_in[4];  const float* bt  = (const float*)d_in[5];
    const float* Wh1 = (const float*)d_in[6];  const float* bh1 = (const float*)d_in[7];
    const float* Wl1 = (const float*)d_in[8];  const float* bl1 = (const float*)d_in[9];
    const float* Wh2 = (const float*)d_in[10]; const float* bh2 = (const float*)d_in[11];
    const float* Wl2 = (const float*)d_in[12]; const float* bl2 = (const float*)d_in[13];
    const float* Wh3 = (const float*)d_in[14]; const float* bh3 = (const float*)d_in[15];
    const float* Wl3 = (const float*)d_in[16]; const float* bl3 = (const float*)d_in[17];
    const float* Wr  = (const float*)d_in[18]; const float* br  = (const float*)d_in[19];
    const float* proto = (const float*)d_in[20];
    float* out = (float*)d_out;

    float* ws = (float*)d_ws;
    size_t off = 0;
    float* e_lt = ws + off; off += (size_t)32 * 512 * 128;   // [(b,l)][h]
    float* e_st = ws + off; off += (size_t)32 * 128 * 128;   // [b,n][h]
    float* O1T = ws + off; off += (size_t)128 * 16384;       // [h][(b,l)]
    float* O2T = ws + off; off += (size_t)256 * 4096;        // [l2][(b,h)]
    float* O3T = ws + off; off += (size_t)128 * 8192;        // [h][(b,l2)]
    float* O4T = ws + off; off += (size_t)128 * 4096;        // [l3][(b,h)]
    float* O5T = ws + off; off += (size_t)128 * 4096;        // [h][(b,l3)]
    float* O6 = ws + off; off += (size_t)32 * 128 * 64;      // [b][h][l4]
    float* part = ws + off; off += (size_t)32 * 128 * 192;
    float* sel_w = ws + off; off += 32;
    int* sel_r = (int*)(ws + off); off += 32;

    encode_kernel<<<dim3(640, 32), 128, 0, stream>>>(in_lt, in_st, Ws, bs, Wt, bt, e_lt, e_st);
    // h1: flat 16384 rows, K=128, N=128 -> O1T[h][16384]
    lbr_wave<128, 128, 2, true><<<dim3(1024, 1), 256, 0, stream>>>(
        e_lt, 128, 0, Wh1, bh1, O1T, 16384, 0);
    // l1: rows=h(128)/b, K=512, N=256; WR=2 (MT=8) -> O2T[l2][4096]
    lbr_wave<512, 256, 2, true><<<dim3(16, 32), 256, 0, stream>>>(
        O1T, 16384, 512, Wl1, bl1, O2T, 4096, 128);
    // h2: rows=l2(256)/b, K=128, N=128; WR=2 (MT=16) -> O3T[h][8192]
    lbr_wave<128, 128, 2, true><<<dim3(16, 32), 256, 0, stream>>>(
        O2T, 4096, 128, Wh2, bh2, O3T, 8192, 256);
    // l2: rows=h(128)/b, K=256, N=128; WR=1 (MT=8) -> O4T[l3][4096]
    lbr_wave<256, 128, 1, true><<<dim3(16, 32), 256, 0, stream>>>(
        O3T, 8192, 256, Wl2, bl2, O4T, 4096, 128);
    // h3: rows=l3(128)/b, K=128, N=128; WR=1 (MT=8) -> O5T[h][4096]
    lbr_wave<128, 128, 1, true><<<dim3(16, 32), 256, 0, stream>>>(
        O4T, 4096, 128, Wh3, bh3, O5T, 4096, 128);
    // l3: rows=h(128)/b, K=128, N=64; natural out [b][h][l4]
    lbr_wave<128, 64, 1, false><<<dim3(8, 32), 256, 0, stream>>>(
        O5T, 4096, 128, Wl3, bl3, O6, 0, 8192);
    logits_select<<<32, 256, 0, stream>>>(O6, Wr, br, sel_w, sel_r);
    einsum_nsplit<<<dim3(128, 8), 192, 0, stream>>>(e_st, proto, sel_r, part);
    finalize_kernel<<<32, 192, 0, stream>>>(part, sel_w, out);
}